// Round 3
// baseline (296.293 us; speedup 1.0000x reference)
//
#include <hip/hip_runtime.h>
#include <hip/hip_bf16.h>

typedef __attribute__((ext_vector_type(8))) __bf16 bf16x8;
typedef __attribute__((ext_vector_type(8))) short short8;
typedef __attribute__((ext_vector_type(4))) float f32x4;

#define LOG2E 1.44269504088896f

static __device__ __forceinline__ ushort f2bf(float f) {
  union { float f; unsigned u; } x; x.f = f;
  unsigned r = x.u + 0x7fffu + ((x.u >> 16) & 1u);
  return (ushort)(r >> 16);
}

// pack 8 fp32 -> 8 bf16 (RNE)
static __device__ __forceinline__ void cvt8(const f32x4 lo, const f32x4 hi, ushort* dst) {
#pragma unroll
  for (int i = 0; i < 4; i++) dst[i] = f2bf(lo[i]);
#pragma unroll
  for (int i = 0; i < 4; i++) dst[4 + i] = f2bf(hi[i]);
}

// ---------------- GEMM: y = A @ W^T + bias ----------------
// MODE 0: A fp32 [4096x768], out bf16 in [B=2,H=12,S=2048,Dk=64] layout (QKV proj)
// MODE 1: A bf16 [4096x768], out fp32 row-major [4096][768] (output proj)
// W fp32 [768x768] (row n = output feature), bias fp32 [768]
template<int MODE>
static __device__ __forceinline__ void gemm_body(const void* __restrict__ Av,
                                                 const float* __restrict__ W,
                                                 const float* __restrict__ bias,
                                                 void* __restrict__ outv)
{
  constexpr int K = 768;
  constexpr int LDA = 40;            // padded LDS row (elements) to spread banks
  __shared__ ushort As[128 * LDA];
  __shared__ ushort Ws[128 * LDA];
  const int tid  = threadIdx.x;
  const int lane = tid & 63;
  const int wid  = tid >> 6;
  const int wr = (wid >> 1) * 64;    // wave row offset in 128x128 tile
  const int wc = (wid & 1) * 64;     // wave col offset
  const int m0 = blockIdx.x * 128;
  const int n0 = blockIdx.y * 128;

  f32x4 acc[4][4];
#pragma unroll
  for (int i = 0; i < 4; i++)
#pragma unroll
    for (int j = 0; j < 4; j++) acc[i][j] = f32x4{0.f, 0.f, 0.f, 0.f};

  const int srow = tid >> 2;             // 0..63
  const int scol = (tid & 3) * 8;        // 0,8,16,24

  const float*  gW  = W + (size_t)(n0 + srow) * K + scol;
  const float*  gAf = (const float*)Av  + (size_t)(m0 + srow) * K + scol;
  const ushort* gAh = (const ushort*)Av + (size_t)(m0 + srow) * K + scol;

  const int fr  = lane & 15;
  const int kg  = (lane >> 4) * 8;

  for (int kt = 0; kt < K; kt += 32) {
    ushort a0[8], a1[8], w0[8], w1[8];
    // W: fp32 -> bf16
    {
      f32x4 lo0 = *(const f32x4*)(gW + kt);
      f32x4 hi0 = *(const f32x4*)(gW + kt + 4);
      f32x4 lo1 = *(const f32x4*)(gW + kt + (size_t)64 * K);
      f32x4 hi1 = *(const f32x4*)(gW + kt + (size_t)64 * K + 4);
      cvt8(lo0, hi0, w0);
      cvt8(lo1, hi1, w1);
    }
    if (MODE == 0) {
      f32x4 lo0 = *(const f32x4*)(gAf + kt);
      f32x4 hi0 = *(const f32x4*)(gAf + kt + 4);
      f32x4 lo1 = *(const f32x4*)(gAf + kt + (size_t)64 * K);
      f32x4 hi1 = *(const f32x4*)(gAf + kt + (size_t)64 * K + 4);
      cvt8(lo0, hi0, a0);
      cvt8(lo1, hi1, a1);
    } else {
      *(short8*)a0 = *(const short8*)(gAh + kt);
      *(short8*)a1 = *(const short8*)(gAh + kt + (size_t)64 * K);
    }
    __syncthreads();                  // previous-iter readers done before overwrite
    *(short8*)&As[srow * LDA + scol]        = *(short8*)a0;
    *(short8*)&As[(srow + 64) * LDA + scol] = *(short8*)a1;
    *(short8*)&Ws[srow * LDA + scol]        = *(short8*)w0;
    *(short8*)&Ws[(srow + 64) * LDA + scol] = *(short8*)w1;
    __syncthreads();

    bf16x8 af[4], wf[4];
#pragma unroll
    for (int i = 0; i < 4; i++) af[i] = *(const bf16x8*)&As[(wr + i * 16 + fr) * LDA + kg];
#pragma unroll
    for (int j = 0; j < 4; j++) wf[j] = *(const bf16x8*)&Ws[(wc + j * 16 + fr) * LDA + kg];
#pragma unroll
    for (int i = 0; i < 4; i++)
#pragma unroll
      for (int j = 0; j < 4; j++)
        acc[i][j] = __builtin_amdgcn_mfma_f32_16x16x32_bf16(af[i], wf[j], acc[i][j], 0, 0, 0);
  }

  // epilogue: bias add + store
#pragma unroll
  for (int i = 0; i < 4; i++) {
#pragma unroll
    for (int j = 0; j < 4; j++) {
#pragma unroll
      for (int r = 0; r < 4; r++) {
        int m = m0 + wr + i * 16 + (lane >> 4) * 4 + r;
        int n = n0 + wc + j * 16 + fr;
        float v = acc[i][j][r] + bias[n];
        if (MODE == 0) {
          int bb = m >> 11, s = m & 2047, hh = n >> 6, dk = n & 63;
          ((ushort*)outv)[(((size_t)bb * 12 + hh) * 2048 + s) * 64 + dk] = f2bf(v);
        } else {
          ((float*)outv)[(size_t)m * 768 + n] = v;
        }
      }
    }
  }
}

__global__ __launch_bounds__(256)
void qkv_gemm(const float* __restrict__ q, const float* __restrict__ k,
              const float* __restrict__ v,
              const float* __restrict__ wq, const float* __restrict__ wk,
              const float* __restrict__ wv,
              const float* __restrict__ bq, const float* __restrict__ bk,
              const float* __restrict__ bv,
              ushort* __restrict__ Qp, ushort* __restrict__ Kp, ushort* __restrict__ Vp)
{
  const int z = blockIdx.z;
  const float* A  = (z == 0) ? q  : (z == 1) ? k  : v;
  const float* W  = (z == 0) ? wq : (z == 1) ? wk : wv;
  const float* Bb = (z == 0) ? bq : (z == 1) ? bk : bv;
  ushort*      O  = (z == 0) ? Qp : (z == 1) ? Kp : Vp;
  gemm_body<0>(A, W, Bb, O);
}

__global__ __launch_bounds__(256)
void o_gemm(const ushort* __restrict__ X, const float* __restrict__ W,
            const float* __restrict__ Bb, float* __restrict__ out)
{
  gemm_body<1>(X, W, Bb, out);
}

// ---------------- Flash attention: bf16 [B,H,S,Dk] -> bf16 X [B,S,768] ----------------
__global__ __launch_bounds__(256)
void attn_kernel(const ushort* __restrict__ Qp, const ushort* __restrict__ Kp,
                 const ushort* __restrict__ Vp, const int* __restrict__ mask,
                 ushort* __restrict__ X)
{
  constexpr int S = 2048;
  __shared__ ushort Ks[64][72];       // K tile, row = key, padded
  __shared__ ushort Vt[64][72];       // V tile transposed: row = dk, col = key
  __shared__ ushort Ps[4][16][72];    // per-wave P tile (q-row x key)

  const int tid  = threadIdx.x;
  const int lane = tid & 63;
  const int w    = tid >> 6;
  const int qb   = blockIdx.x;        // 0..31
  const int bh   = blockIdx.y;        // 0..23
  const int b    = bh / 12, h = bh % 12;

  const ushort* Qb = Qp + (size_t)bh * S * 64;
  const ushort* Kb = Kp + (size_t)bh * S * 64;
  const ushort* Vb = Vp + (size_t)bh * S * 64;

  const int q0  = qb * 64;
  const int fr  = lane & 15;
  const int kg8 = (lane >> 4) * 8;

  // Q fragments hoisted to registers (wave owns q-rows q0+w*16 .. +15)
  const int qrow = q0 + w * 16 + fr;
  bf16x8 qf[2];
  qf[0] = *(const bf16x8*)&Qb[(size_t)qrow * 64 + kg8];
  qf[1] = *(const bf16x8*)&Qb[(size_t)qrow * 64 + 32 + kg8];

  float m_r[4] = {-1e9f, -1e9f, -1e9f, -1e9f};
  float l_r[4] = {0.f, 0.f, 0.f, 0.f};
  f32x4 accO[4];
#pragma unroll
  for (int ni = 0; ni < 4; ni++) accO[ni] = f32x4{0.f, 0.f, 0.f, 0.f};

  const int skey = tid >> 2;          // 0..63
  const int sc0  = (tid & 3) * 16;    // 0,16,32,48
  const size_t mrow_base = (size_t)(q0 + w * 16 + (lane >> 4) * 4) * S;

  for (int k0 = 0; k0 < S; k0 += 64) {
    short8 kv0 = *(const short8*)&Kb[(size_t)(k0 + skey) * 64 + sc0];
    short8 kv1 = *(const short8*)&Kb[(size_t)(k0 + skey) * 64 + sc0 + 8];
    short8 vv0 = *(const short8*)&Vb[(size_t)(k0 + skey) * 64 + sc0];
    short8 vv1 = *(const short8*)&Vb[(size_t)(k0 + skey) * 64 + sc0 + 8];
    __syncthreads();
    *(short8*)&Ks[skey][sc0]     = kv0;
    *(short8*)&Ks[skey][sc0 + 8] = kv1;
#pragma unroll
    for (int i = 0; i < 8; i++) {
      Vt[sc0 + i][skey]     = (ushort)vv0[i];
      Vt[sc0 + 8 + i][skey] = (ushort)vv1[i];
    }
    __syncthreads();

    // QK^T: scores[q=(lane>>4)*4+r][key=ni*16+fr]
    f32x4 sc4[4];
#pragma unroll
    for (int ni = 0; ni < 4; ni++) {
      bf16x8 kf0 = *(const bf16x8*)&Ks[ni * 16 + fr][kg8];
      bf16x8 kf1 = *(const bf16x8*)&Ks[ni * 16 + fr][32 + kg8];
      f32x4 c = {0.f, 0.f, 0.f, 0.f};
      c = __builtin_amdgcn_mfma_f32_16x16x32_bf16(qf[0], kf0, c, 0, 0, 0);
      c = __builtin_amdgcn_mfma_f32_16x16x32_bf16(qf[1], kf1, c, 0, 0, 0);
      sc4[ni] = c;
    }

    // scale + mask
    float p[4][4]; // [ni][r]
#pragma unroll
    for (int r = 0; r < 4; r++) {
#pragma unroll
      for (int ni = 0; ni < 4; ni++) {
        int mk = mask[mrow_base + (size_t)r * S + k0 + ni * 16 + fr];
        float s = sc4[ni][r] * 0.125f;
        p[ni][r] = mk ? s : -1e9f;
      }
    }

    // online softmax per q-row r (reduce across the 16-lane group)
#pragma unroll
    for (int r = 0; r < 4; r++) {
      float mx = fmaxf(fmaxf(p[0][r], p[1][r]), fmaxf(p[2][r], p[3][r]));
      mx = fmaxf(mx, __shfl_xor(mx, 1));
      mx = fmaxf(mx, __shfl_xor(mx, 2));
      mx = fmaxf(mx, __shfl_xor(mx, 4));
      mx = fmaxf(mx, __shfl_xor(mx, 8));
      float mn = fmaxf(m_r[r], mx);
      float al = exp2f((m_r[r] - mn) * LOG2E);
      m_r[r] = mn;
      float ls = 0.f;
#pragma unroll
      for (int ni = 0; ni < 4; ni++) {
        float e = exp2f((p[ni][r] - mn) * LOG2E);
        p[ni][r] = e;
        ls += e;
      }
      ls += __shfl_xor(ls, 1);
      ls += __shfl_xor(ls, 2);
      ls += __shfl_xor(ls, 4);
      ls += __shfl_xor(ls, 8);
      l_r[r] = l_r[r] * al + ls;
#pragma unroll
      for (int ni = 0; ni < 4; ni++) accO[ni][r] *= al;
    }

    // P -> LDS (to reach MFMA A-operand layout)
#pragma unroll
    for (int r = 0; r < 4; r++)
#pragma unroll
      for (int ni = 0; ni < 4; ni++)
        Ps[w][(lane >> 4) * 4 + r][ni * 16 + fr] = f2bf(p[ni][r]);

    // PV: O[q][dk] += P[q][key] V[key][dk]
#pragma unroll
    for (int ks = 0; ks < 2; ks++) {
      bf16x8 pf = *(const bf16x8*)&Ps[w][fr][ks * 32 + kg8];
#pragma unroll
      for (int ni = 0; ni < 4; ni++) {
        bf16x8 vf = *(const bf16x8*)&Vt[ni * 16 + fr][ks * 32 + kg8];
        accO[ni] = __builtin_amdgcn_mfma_f32_16x16x32_bf16(pf, vf, accO[ni], 0, 0, 0);
      }
    }
  }

  // normalize + store X[b][q][h*64+dk] (bf16 workspace)
#pragma unroll
  for (int ni = 0; ni < 4; ni++) {
#pragma unroll
    for (int r = 0; r < 4; r++) {
      int qq = q0 + w * 16 + (lane >> 4) * 4 + r;
      float o = accO[ni][r] / l_r[r];
      X[((size_t)b * S + qq) * 768 + h * 64 + ni * 16 + fr] = f2bf(o);
    }
  }
}

extern "C" void kernel_launch(void* const* d_in, const int* in_sizes, int n_in,
                              void* d_out, int out_size, void* d_ws, size_t ws_size,
                              hipStream_t stream) {
  const float* q  = (const float*)d_in[0];
  const float* k  = (const float*)d_in[1];
  const float* v  = (const float*)d_in[2];
  const int* mask = (const int*)d_in[3];
  const float* wq = (const float*)d_in[4];
  const float* bq = (const float*)d_in[5];
  const float* wk = (const float*)d_in[6];
  const float* bk = (const float*)d_in[7];
  const float* wv = (const float*)d_in[8];
  const float* bv = (const float*)d_in[9];
  const float* wo = (const float*)d_in[10];
  const float* bo = (const float*)d_in[11];
  float* out = (float*)d_out;

  const size_t PROJ = (size_t)2 * 12 * 2048 * 64;  // 3,145,728 elems (bf16)
  ushort* Qp = (ushort*)d_ws;
  ushort* Kp = Qp + PROJ;
  ushort* Vp = Kp + PROJ;
  ushort* Xb = Vp + PROJ;   // total ws use: 4 * 6.29 MB = 25.2 MB

  qkv_gemm<<<dim3(32, 6, 3), dim3(256), 0, stream>>>(q, k, v, wq, wk, wv, bq, bk, bv, Qp, Kp, Vp);
  attn_kernel<<<dim3(32, 24), dim3(256), 0, stream>>>(Qp, Kp, Vp, mask, Xb);
  o_gemm<<<dim3(32, 6), dim3(256), 0, stream>>>(Xb, wo, bo, out);
}

// Round 4
// 278.083 us; speedup vs baseline: 1.0655x; 1.0655x over previous
//
#include <hip/hip_runtime.h>
#include <hip/hip_bf16.h>

typedef __attribute__((ext_vector_type(8))) __bf16 bf16x8;
typedef __attribute__((ext_vector_type(8))) short short8;
typedef __attribute__((ext_vector_type(4))) float f32x4;
typedef __attribute__((ext_vector_type(4))) ushort us4;

#define LOG2E 1.44269504088896f

static __device__ __forceinline__ ushort f2bf(float f) {
  union { float f; unsigned u; } x; x.f = f;
  unsigned r = x.u + 0x7fffu + ((x.u >> 16) & 1u);
  return (ushort)(r >> 16);
}

static __device__ __forceinline__ void gll16(const ushort* g, ushort* l) {
  __builtin_amdgcn_global_load_lds(
      (const __attribute__((address_space(1))) unsigned*)g,
      (__attribute__((address_space(3))) unsigned*)l, 16, 0, 0);
}

// ---------------- fp32 -> bf16 conversion / packing pre-pass ----------------
// dst layout (ushort elems): [Qin NQ][Kin NQ][Vin NQ][Wq NW][Wk NW][Wv NW][Wo NW]
#define NQ 3145728u
#define NW 589824u
__global__ __launch_bounds__(256)
void cvt_all(const float* __restrict__ q, const float* __restrict__ k,
             const float* __restrict__ v,
             const float* __restrict__ wq, const float* __restrict__ wk,
             const float* __restrict__ wv, const float* __restrict__ wo,
             ushort* __restrict__ dst)
{
  size_t i = ((size_t)blockIdx.x * 256 + threadIdx.x) * 4;
  const float* src; size_t off;
  if (i < NQ)            { src = q; off = i; }
  else if (i < 2u * NQ)  { src = k; off = i - NQ; }
  else if (i < 3u * NQ)  { src = v; off = i - 2u * NQ; }
  else {
    size_t j = i - 3u * NQ;
    unsigned wsel = (unsigned)(j / NW);
    off = j % NW;
    src = (wsel == 0) ? wq : (wsel == 1) ? wk : (wsel == 2) ? wv : wo;
  }
  f32x4 x = *(const f32x4*)(src + off);
  us4 o;
#pragma unroll
  for (int t = 0; t < 4; t++) o[t] = f2bf(x[t]);
  *(us4*)(dst + i) = o;
}

// ---------------- m97-structure GEMM: y = A @ W^T + bias (all-bf16 operands) ----------------
// A bf16 [4096][768]; Wrow0 = weight rows starting at global output-col n0, bf16 [.][768]
// MODE 0: out bf16 [B=2,H=12,S=2048,Dk=64] (QKV proj; c0 = col within the 768-wide proj)
// MODE 1: out fp32 row-major [4096][768] (c0 = n0)
template<int MODE>
static __device__ __forceinline__ void gemm_core(const ushort* __restrict__ A,
                                                 const ushort* __restrict__ Wrow0,
                                                 const float* __restrict__ bias0,
                                                 void* __restrict__ outv,
                                                 int m0, int c0)
{
  constexpr int K = 768;
  __shared__ ushort As[128 * 32];   // linear: global_load_lds needs contiguous lane order
  __shared__ ushort Bs[128 * 32];
  const int tid  = threadIdx.x;
  const int lane = tid & 63;
  const int wid  = tid >> 6;
  const int wr = (wid >> 1) * 64;
  const int wc = (wid & 1) * 64;

  f32x4 acc[4][4];
#pragma unroll
  for (int i = 0; i < 4; i++)
#pragma unroll
    for (int j = 0; j < 4; j++) acc[i][j] = f32x4{0.f, 0.f, 0.f, 0.f};

  // staging: wave w + region r covers LDS bytes [(r*4+w)*1024, +1024): row = r*64 + w*16 + l/4, col = (l&3)*8
  const int srow = wid * 16 + (lane >> 2);   // 0..63
  const int scol = (lane & 3) * 8;
  const ushort* gA0 = A     + (size_t)(m0 + srow) * K + scol;
  const ushort* gA1 = gA0 + (size_t)64 * K;
  const ushort* gB0 = Wrow0 + (size_t)srow * K + scol;
  const ushort* gB1 = gB0 + (size_t)64 * K;
  ushort* lA0 = &As[srow * 32 + scol];
  ushort* lA1 = &As[(srow + 64) * 32 + scol];
  ushort* lB0 = &Bs[srow * 32 + scol];
  ushort* lB1 = &Bs[(srow + 64) * 32 + scol];

  const int fr  = lane & 15;
  const int kg8 = (lane >> 4) * 8;

  for (int kt = 0; kt < K; kt += 32) {
    __syncthreads();                 // prior iter's ds_reads done before overwrite
    gll16(gA0 + kt, lA0);
    gll16(gA1 + kt, lA1);
    gll16(gB0 + kt, lB0);
    gll16(gB1 + kt, lB1);
    __syncthreads();                 // vmcnt(0) drain -> tile resident

    bf16x8 af[4], wf[4];
#pragma unroll
    for (int i = 0; i < 4; i++) af[i] = *(const bf16x8*)&As[(wr + i * 16 + fr) * 32 + kg8];
#pragma unroll
    for (int j = 0; j < 4; j++) wf[j] = *(const bf16x8*)&Bs[(wc + j * 16 + fr) * 32 + kg8];
#pragma unroll
    for (int i = 0; i < 4; i++)
#pragma unroll
      for (int j = 0; j < 4; j++)
        acc[i][j] = __builtin_amdgcn_mfma_f32_16x16x32_bf16(af[i], wf[j], acc[i][j], 0, 0, 0);
  }

  // epilogue: bias + store
#pragma unroll
  for (int i = 0; i < 4; i++) {
#pragma unroll
    for (int j = 0; j < 4; j++) {
#pragma unroll
      for (int r = 0; r < 4; r++) {
        int m  = m0 + wr + i * 16 + (lane >> 4) * 4 + r;
        int lc = wc + j * 16 + fr;
        float val = acc[i][j][r] + bias0[lc];
        if (MODE == 0) {
          int nn = c0 + lc;
          int hh = nn >> 6, dk = nn & 63;
          ((ushort*)outv)[(((size_t)(m >> 11) * 12 + hh) * 2048 + (m & 2047)) * 64 + dk] = f2bf(val);
        } else {
          ((float*)outv)[(size_t)m * 768 + c0 + lc] = val;
        }
      }
    }
  }
}

__global__ __launch_bounds__(256)
void qkv_gemm2(const ushort* __restrict__ CV,      // converted buffer base
               const float* __restrict__ bq, const float* __restrict__ bk,
               const float* __restrict__ bv,
               ushort* __restrict__ Qp, ushort* __restrict__ Kp, ushort* __restrict__ Vp)
{
  const int m0 = blockIdx.x * 128;
  const int n0 = blockIdx.y * 128;        // 0..2303 (global feature col across q,k,v)
  const int proj = n0 / 768;
  const int c0 = n0 - proj * 768;
  const ushort* A  = CV + (size_t)proj * NQ;
  const ushort* Wc = CV + (size_t)3 * NQ; // packed weights [3072][768]
  const float* bias = (proj == 0) ? bq : (proj == 1) ? bk : bv;
  ushort* O = (proj == 0) ? Qp : (proj == 1) ? Kp : Vp;
  gemm_core<0>(A, Wc + (size_t)n0 * 768, bias + c0, O, m0, c0);
}

__global__ __launch_bounds__(256)
void o_gemm2(const ushort* __restrict__ X, const ushort* __restrict__ Wo,
             const float* __restrict__ bo, float* __restrict__ out)
{
  const int m0 = blockIdx.x * 128;
  const int n0 = blockIdx.y * 128;
  gemm_core<1>(X, Wo + (size_t)n0 * 768, bo + n0, out, m0, n0);
}

// ---------------- Flash attention: bf16 [B,H,S,Dk] -> bf16 X [B,S,768] ----------------
__global__ __launch_bounds__(256)
void attn_kernel(const ushort* __restrict__ Qp, const ushort* __restrict__ Kp,
                 const ushort* __restrict__ Vp, const int* __restrict__ mask,
                 ushort* __restrict__ X)
{
  constexpr int S = 2048;
  __shared__ ushort Ks[64][72];       // K tile, row = key, padded
  __shared__ ushort Vt[64][72];       // V tile transposed: row = dk, col = key
  __shared__ ushort Ps[4][16][72];    // per-wave P tile (q-row x key)

  const int tid  = threadIdx.x;
  const int lane = tid & 63;
  const int w    = tid >> 6;
  const int qb   = blockIdx.x;        // 0..31
  const int bh   = blockIdx.y;        // 0..23
  const int b    = bh / 12, h = bh % 12;

  const ushort* Qb = Qp + (size_t)bh * S * 64;
  const ushort* Kb = Kp + (size_t)bh * S * 64;
  const ushort* Vb = Vp + (size_t)bh * S * 64;

  const int q0  = qb * 64;
  const int fr  = lane & 15;
  const int kg8 = (lane >> 4) * 8;

  const int qrow = q0 + w * 16 + fr;
  bf16x8 qf[2];
  qf[0] = *(const bf16x8*)&Qb[(size_t)qrow * 64 + kg8];
  qf[1] = *(const bf16x8*)&Qb[(size_t)qrow * 64 + 32 + kg8];

  float m_r[4] = {-1e9f, -1e9f, -1e9f, -1e9f};
  float l_r[4] = {0.f, 0.f, 0.f, 0.f};
  f32x4 accO[4];
#pragma unroll
  for (int ni = 0; ni < 4; ni++) accO[ni] = f32x4{0.f, 0.f, 0.f, 0.f};

  const int skey = tid >> 2;          // 0..63
  const int sc0  = (tid & 3) * 16;    // 0,16,32,48
  const size_t mrow_base = (size_t)(q0 + w * 16 + (lane >> 4) * 4) * S;

  for (int k0 = 0; k0 < S; k0 += 64) {
    short8 kv0 = *(const short8*)&Kb[(size_t)(k0 + skey) * 64 + sc0];
    short8 kv1 = *(const short8*)&Kb[(size_t)(k0 + skey) * 64 + sc0 + 8];
    short8 vv0 = *(const short8*)&Vb[(size_t)(k0 + skey) * 64 + sc0];
    short8 vv1 = *(const short8*)&Vb[(size_t)(k0 + skey) * 64 + sc0 + 8];
    __syncthreads();
    *(short8*)&Ks[skey][sc0]     = kv0;
    *(short8*)&Ks[skey][sc0 + 8] = kv1;
#pragma unroll
    for (int i = 0; i < 8; i++) {
      Vt[sc0 + i][skey]     = (ushort)vv0[i];
      Vt[sc0 + 8 + i][skey] = (ushort)vv1[i];
    }
    __syncthreads();

    f32x4 sc4[4];
#pragma unroll
    for (int ni = 0; ni < 4; ni++) {
      bf16x8 kf0 = *(const bf16x8*)&Ks[ni * 16 + fr][kg8];
      bf16x8 kf1 = *(const bf16x8*)&Ks[ni * 16 + fr][32 + kg8];
      f32x4 c = {0.f, 0.f, 0.f, 0.f};
      c = __builtin_amdgcn_mfma_f32_16x16x32_bf16(qf[0], kf0, c, 0, 0, 0);
      c = __builtin_amdgcn_mfma_f32_16x16x32_bf16(qf[1], kf1, c, 0, 0, 0);
      sc4[ni] = c;
    }

    float p[4][4]; // [ni][r]
#pragma unroll
    for (int r = 0; r < 4; r++) {
#pragma unroll
      for (int ni = 0; ni < 4; ni++) {
        int mk = mask[mrow_base + (size_t)r * S + k0 + ni * 16 + fr];
        float s = sc4[ni][r] * 0.125f;
        p[ni][r] = mk ? s : -1e9f;
      }
    }

#pragma unroll
    for (int r = 0; r < 4; r++) {
      float mx = fmaxf(fmaxf(p[0][r], p[1][r]), fmaxf(p[2][r], p[3][r]));
      mx = fmaxf(mx, __shfl_xor(mx, 1));
      mx = fmaxf(mx, __shfl_xor(mx, 2));
      mx = fmaxf(mx, __shfl_xor(mx, 4));
      mx = fmaxf(mx, __shfl_xor(mx, 8));
      float mn = fmaxf(m_r[r], mx);
      float al = exp2f((m_r[r] - mn) * LOG2E);
      m_r[r] = mn;
      float ls = 0.f;
#pragma unroll
      for (int ni = 0; ni < 4; ni++) {
        float e = exp2f((p[ni][r] - mn) * LOG2E);
        p[ni][r] = e;
        ls += e;
      }
      ls += __shfl_xor(ls, 1);
      ls += __shfl_xor(ls, 2);
      ls += __shfl_xor(ls, 4);
      ls += __shfl_xor(ls, 8);
      l_r[r] = l_r[r] * al + ls;
#pragma unroll
      for (int ni = 0; ni < 4; ni++) accO[ni][r] *= al;
    }

#pragma unroll
    for (int r = 0; r < 4; r++)
#pragma unroll
      for (int ni = 0; ni < 4; ni++)
        Ps[w][(lane >> 4) * 4 + r][ni * 16 + fr] = f2bf(p[ni][r]);

#pragma unroll
    for (int ks = 0; ks < 2; ks++) {
      bf16x8 pf = *(const bf16x8*)&Ps[w][fr][ks * 32 + kg8];
#pragma unroll
      for (int ni = 0; ni < 4; ni++) {
        bf16x8 vf = *(const bf16x8*)&Vt[ni * 16 + fr][ks * 32 + kg8];
        accO[ni] = __builtin_amdgcn_mfma_f32_16x16x32_bf16(pf, vf, accO[ni], 0, 0, 0);
      }
    }
  }

#pragma unroll
  for (int ni = 0; ni < 4; ni++) {
#pragma unroll
    for (int r = 0; r < 4; r++) {
      int qq = q0 + w * 16 + (lane >> 4) * 4 + r;
      float o = accO[ni][r] / l_r[r];
      X[((size_t)b * S + qq) * 768 + h * 64 + ni * 16 + fr] = f2bf(o);
    }
  }
}

extern "C" void kernel_launch(void* const* d_in, const int* in_sizes, int n_in,
                              void* d_out, int out_size, void* d_ws, size_t ws_size,
                              hipStream_t stream) {
  const float* q  = (const float*)d_in[0];
  const float* k  = (const float*)d_in[1];
  const float* v  = (const float*)d_in[2];
  const int* mask = (const int*)d_in[3];
  const float* wq = (const float*)d_in[4];
  const float* bq = (const float*)d_in[5];
  const float* wk = (const float*)d_in[6];
  const float* bk = (const float*)d_in[7];
  const float* wv = (const float*)d_in[8];
  const float* bv = (const float*)d_in[9];
  const float* wo = (const float*)d_in[10];
  const float* bo = (const float*)d_in[11];
  float* out = (float*)d_out;

  // ws layout (ushort elems): CV [3*NQ + 4*NW] | Qp [NQ] | Kp [NQ] | Vp [NQ] | Xb [NQ]
  ushort* CV = (ushort*)d_ws;
  ushort* Qp = CV + (size_t)3 * NQ + (size_t)4 * NW;
  ushort* Kp = Qp + NQ;
  ushort* Vp = Kp + NQ;
  ushort* Xb = Vp + NQ;   // total ~48.7 MB

  cvt_all<<<11520, 256, 0, stream>>>(q, k, v, wq, wk, wv, wo, CV);
  qkv_gemm2<<<dim3(32, 18), dim3(256), 0, stream>>>(CV, bq, bk, bv, Qp, Kp, Vp);
  attn_kernel<<<dim3(32, 24), dim3(256), 0, stream>>>(Qp, Kp, Vp, mask, Xb);
  o_gemm2<<<dim3(32, 6), dim3(256), 0, stream>>>(Xb, CV + (size_t)3 * NQ + (size_t)3 * NW, bo, out);
}

// Round 6
// 264.143 us; speedup vs baseline: 1.1217x; 1.0528x over previous
//
#include <hip/hip_runtime.h>
#include <hip/hip_bf16.h>

typedef __attribute__((ext_vector_type(8))) __bf16 bf16x8;
typedef __attribute__((ext_vector_type(8))) short short8;
typedef __attribute__((ext_vector_type(4))) float f32x4;

#define LOG2E 1.44269504088896f
#define SCL (0.125f * 1.44269504088896f)   // combine 1/sqrt(64) with log2 domain

static __device__ __forceinline__ ushort f2bf(float f) {
  union { float f; unsigned u; } x; x.f = f;
  unsigned r = x.u + 0x7fffu + ((x.u >> 16) & 1u);
  return (ushort)(r >> 16);
}

static __device__ __forceinline__ unsigned cvt_pk_bf16(float a, float b) {
  unsigned r;
  asm("v_cvt_pk_bf16_f32 %0, %1, %2" : "=v"(r) : "v"(a), "v"(b));
  return r;
}

static __device__ __forceinline__ void gll16(const ushort* g, ushort* l) {
  __builtin_amdgcn_global_load_lds(
      (const __attribute__((address_space(1))) unsigned*)g,
      (__attribute__((address_space(3))) unsigned*)l, 16, 0, 0);
}

// ---------------- fp32 -> bf16 conversion / packing pre-pass ----------------
#define NQ 3145728u
#define NW 589824u
__global__ __launch_bounds__(256)
void cvt_all(const float* __restrict__ q, const float* __restrict__ k,
             const float* __restrict__ v,
             const float* __restrict__ wq, const float* __restrict__ wk,
             const float* __restrict__ wv, const float* __restrict__ wo,
             ushort* __restrict__ dst)
{
  size_t i = ((size_t)blockIdx.x * 256 + threadIdx.x) * 4;
  const float* src; size_t off;
  if (i < NQ)            { src = q; off = i; }
  else if (i < 2u * NQ)  { src = k; off = i - NQ; }
  else if (i < 3u * NQ)  { src = v; off = i - 2u * NQ; }
  else {
    size_t j = i - 3u * NQ;
    unsigned wsel = (unsigned)(j / NW);
    off = j % NW;
    src = (wsel == 0) ? wq : (wsel == 1) ? wk : (wsel == 2) ? wv : wo;
  }
  f32x4 x = *(const f32x4*)(src + off);
  uint2 o;
  o.x = cvt_pk_bf16(x[0], x[1]);
  o.y = cvt_pk_bf16(x[2], x[3]);
  *(uint2*)(dst + i) = o;
}

// ---------------- mask bit-pack: int32[2048][2048] -> u64[2048][32] ----------------
__global__ __launch_bounds__(256)
void mask_pack(const int* __restrict__ mask, unsigned long long* __restrict__ mb)
{
  size_t gw = (size_t)blockIdx.x * 4 + (threadIdx.x >> 6);  // u64 index, 0..65535
  int lane = threadIdx.x & 63;
  int mk = mask[gw * 64 + lane];
  unsigned long long bits = __ballot(mk != 0);
  if (lane == 0) mb[gw] = bits;
}

// ---------------- m97-structure GEMM: y = A @ W^T + bias (all-bf16 operands) ----------------
template<int MODE>
static __device__ __forceinline__ void gemm_core(const ushort* __restrict__ A,
                                                 const ushort* __restrict__ Wrow0,
                                                 const float* __restrict__ bias0,
                                                 void* __restrict__ outv,
                                                 int m0, int c0)
{
  constexpr int K = 768;
  __shared__ ushort As[128 * 32];
  __shared__ ushort Bs[128 * 32];
  const int tid  = threadIdx.x;
  const int lane = tid & 63;
  const int wid  = tid >> 6;
  const int wr = (wid >> 1) * 64;
  const int wc = (wid & 1) * 64;

  f32x4 acc[4][4];
#pragma unroll
  for (int i = 0; i < 4; i++)
#pragma unroll
    for (int j = 0; j < 4; j++) acc[i][j] = f32x4{0.f, 0.f, 0.f, 0.f};

  const int srow = wid * 16 + (lane >> 2);
  const int scol = (lane & 3) * 8;
  const ushort* gA0 = A     + (size_t)(m0 + srow) * K + scol;
  const ushort* gA1 = gA0 + (size_t)64 * K;
  const ushort* gB0 = Wrow0 + (size_t)srow * K + scol;
  const ushort* gB1 = gB0 + (size_t)64 * K;
  ushort* lA0 = &As[srow * 32 + scol];
  ushort* lA1 = &As[(srow + 64) * 32 + scol];
  ushort* lB0 = &Bs[srow * 32 + scol];
  ushort* lB1 = &Bs[(srow + 64) * 32 + scol];

  const int fr  = lane & 15;
  const int kg8 = (lane >> 4) * 8;

  for (int kt = 0; kt < K; kt += 32) {
    __syncthreads();
    gll16(gA0 + kt, lA0);
    gll16(gA1 + kt, lA1);
    gll16(gB0 + kt, lB0);
    gll16(gB1 + kt, lB1);
    __syncthreads();

    bf16x8 af[4], wf[4];
#pragma unroll
    for (int i = 0; i < 4; i++) af[i] = *(const bf16x8*)&As[(wr + i * 16 + fr) * 32 + kg8];
#pragma unroll
    for (int j = 0; j < 4; j++) wf[j] = *(const bf16x8*)&Bs[(wc + j * 16 + fr) * 32 + kg8];
#pragma unroll
    for (int i = 0; i < 4; i++)
#pragma unroll
      for (int j = 0; j < 4; j++)
        acc[i][j] = __builtin_amdgcn_mfma_f32_16x16x32_bf16(af[i], wf[j], acc[i][j], 0, 0, 0);
  }

#pragma unroll
  for (int i = 0; i < 4; i++) {
#pragma unroll
    for (int j = 0; j < 4; j++) {
#pragma unroll
      for (int r = 0; r < 4; r++) {
        int m  = m0 + wr + i * 16 + (lane >> 4) * 4 + r;
        int lc = wc + j * 16 + fr;
        float val = acc[i][j][r] + bias0[lc];
        if (MODE == 0) {
          int nn = c0 + lc;
          int hh = nn >> 6, dk = nn & 63;
          ((ushort*)outv)[(((size_t)(m >> 11) * 12 + hh) * 2048 + (m & 2047)) * 64 + dk] = f2bf(val);
        } else {
          ((float*)outv)[(size_t)m * 768 + c0 + lc] = val;
        }
      }
    }
  }
}

__global__ __launch_bounds__(256)
void qkv_gemm2(const ushort* __restrict__ CV,
               const float* __restrict__ bq, const float* __restrict__ bk,
               const float* __restrict__ bv,
               ushort* __restrict__ Qp, ushort* __restrict__ Kp, ushort* __restrict__ Vp)
{
  const int m0 = blockIdx.x * 128;
  const int n0 = blockIdx.y * 128;
  const int proj = n0 / 768;
  const int c0 = n0 - proj * 768;
  const ushort* A  = CV + (size_t)proj * NQ;
  const ushort* Wc = CV + (size_t)3 * NQ;
  const float* bias = (proj == 0) ? bq : (proj == 1) ? bk : bv;
  ushort* O = (proj == 0) ? Qp : (proj == 1) ? Kp : Vp;
  gemm_core<0>(A, Wc + (size_t)n0 * 768, bias + c0, O, m0, c0);
}

__global__ __launch_bounds__(256)
void o_gemm2(const ushort* __restrict__ X, const ushort* __restrict__ Wo,
             const float* __restrict__ bo, float* __restrict__ out)
{
  const int m0 = blockIdx.x * 128;
  const int n0 = blockIdx.y * 128;
  gemm_core<1>(X, Wo + (size_t)n0 * 768, bo + n0, out, m0, n0);
}

// ---------------- Flash attention v2: KVBLK=128, bitmask, prefetch ----------------
__global__ __launch_bounds__(256, 3)
void attn_kernel(const ushort* __restrict__ Qp, const ushort* __restrict__ Kp,
                 const ushort* __restrict__ Vp,
                 const unsigned long long* __restrict__ mb,
                 ushort* __restrict__ X)
{
  constexpr int S = 2048;
  __shared__ ushort Ks[128][72];      // key-major K tile
  __shared__ ushort Vt[64][136];      // d-major (transposed) V tile
  __shared__ ushort Ps[4][16][136];   // per-wave P tile

  const int tid  = threadIdx.x;
  const int lane = tid & 63;
  const int w    = tid >> 6;
  const int bid  = blockIdx.x;
  // XCD swizzle: all 32 q-blocks of one (b,h) land on one XCD
  const int bh = (bid & 7) + 8 * (bid >> 8);
  const int qb = (bid >> 3) & 31;
  const int b = bh / 12, h = bh % 12;

  const ushort* Qb = Qp + (size_t)bh * S * 64;
  const ushort* Kb = Kp + (size_t)bh * S * 64;
  const ushort* Vb = Vp + (size_t)bh * S * 64;

  const int q0  = qb * 64;
  const int fr  = lane & 15;
  const int g   = lane >> 4;
  const int kg8 = g * 8;
  const int qrow4 = q0 + w * 16 + g * 4;

  const int qrow = q0 + w * 16 + fr;
  bf16x8 qf0 = *(const bf16x8*)&Qb[(size_t)qrow * 64 + kg8];
  bf16x8 qf1 = *(const bf16x8*)&Qb[(size_t)qrow * 64 + 32 + kg8];

  float m_r[4] = {-1e9f, -1e9f, -1e9f, -1e9f};
  float l_r[4] = {0.f, 0.f, 0.f, 0.f};
  f32x4 accO[4];
#pragma unroll
  for (int ni = 0; ni < 4; ni++) accO[ni] = f32x4{0.f, 0.f, 0.f, 0.f};

  const int skey = tid >> 2;          // 0..63
  const int sc0  = (tid & 3) * 16;
  const uint4* mb4 = (const uint4*)mb;

  short8 kr0, kr1, kr2, kr3, vr0, vr1, vr2, vr3;
  {
    const ushort* kb = Kb + (size_t)skey * 64 + sc0;
    const ushort* vb = Vb + (size_t)skey * 64 + sc0;
    kr0 = *(const short8*)kb;          kr1 = *(const short8*)(kb + 8);
    kr2 = *(const short8*)(kb + 4096); kr3 = *(const short8*)(kb + 4104);
    vr0 = *(const short8*)vb;          vr1 = *(const short8*)(vb + 8);
    vr2 = *(const short8*)(vb + 4096); vr3 = *(const short8*)(vb + 4104);
  }

  for (int tt = 0; tt < 16; tt++) {
    __syncthreads();                  // prior tile's LDS consumers done
    *(short8*)&Ks[skey][sc0]          = kr0;
    *(short8*)&Ks[skey][sc0 + 8]      = kr1;
    *(short8*)&Ks[64 + skey][sc0]     = kr2;
    *(short8*)&Ks[64 + skey][sc0 + 8] = kr3;
#pragma unroll
    for (int i = 0; i < 8; i++) {
      Vt[sc0 + i][skey]          = (ushort)vr0[i];
      Vt[sc0 + 8 + i][skey]      = (ushort)vr1[i];
      Vt[sc0 + i][64 + skey]     = (ushort)vr2[i];
      Vt[sc0 + 8 + i][64 + skey] = (ushort)vr3[i];
    }
    __syncthreads();

    // mask bits for this tile: 128 bits per q-row (broadcast load per 16-lane group)
    // row stride = 32 u64 = 16 uint4  (R5 bug: was *8)
    uint4 mB[4];
#pragma unroll
    for (int r = 0; r < 4; r++)
      mB[r] = mb4[(size_t)(qrow4 + r) * 16 + tt];

    // prefetch next K/V tile into registers (latency hidden under MFMAs)
    if (tt < 15) {
      const ushort* kb = Kb + (size_t)((tt + 1) * 128 + skey) * 64 + sc0;
      const ushort* vb = Vb + (size_t)((tt + 1) * 128 + skey) * 64 + sc0;
      kr0 = *(const short8*)kb;          kr1 = *(const short8*)(kb + 8);
      kr2 = *(const short8*)(kb + 4096); kr3 = *(const short8*)(kb + 4104);
      vr0 = *(const short8*)vb;          vr1 = *(const short8*)(vb + 8);
      vr2 = *(const short8*)(vb + 4096); vr3 = *(const short8*)(vb + 4104);
    }

    // QK^T: 8 key-chunks of 16
    f32x4 sc8[8];
#pragma unroll
    for (int ni = 0; ni < 8; ni++) {
      bf16x8 kf0 = *(const bf16x8*)&Ks[ni * 16 + fr][kg8];
      bf16x8 kf1 = *(const bf16x8*)&Ks[ni * 16 + fr][32 + kg8];
      f32x4 c = {0.f, 0.f, 0.f, 0.f};
      c = __builtin_amdgcn_mfma_f32_16x16x32_bf16(qf0, kf0, c, 0, 0, 0);
      c = __builtin_amdgcn_mfma_f32_16x16x32_bf16(qf1, kf1, c, 0, 0, 0);
      sc8[ni] = c;
    }

    // online softmax per q-row (log2 domain; max over raw scores is a valid bound)
#pragma unroll
    for (int r = 0; r < 4; r++) {
      float praw[8];
#pragma unroll
      for (int ni = 0; ni < 8; ni++) praw[ni] = sc8[ni][r] * SCL;
      float mx = fmaxf(fmaxf(fmaxf(praw[0], praw[1]), fmaxf(praw[2], praw[3])),
                       fmaxf(fmaxf(praw[4], praw[5]), fmaxf(praw[6], praw[7])));
      mx = fmaxf(mx, __shfl_xor(mx, 1));
      mx = fmaxf(mx, __shfl_xor(mx, 2));
      mx = fmaxf(mx, __shfl_xor(mx, 4));
      mx = fmaxf(mx, __shfl_xor(mx, 8));
      if (mx > m_r[r] + 11.5f) {       // defer-rescale (T13): P bounded by 2^11.5
        float al = exp2f(m_r[r] - mx);
        m_r[r] = mx;
        l_r[r] *= al;
#pragma unroll
        for (int ni = 0; ni < 4; ni++) accO[ni][r] *= al;
      }
      const float mr = m_r[r];
      unsigned sx = mB[r].x >> fr, sy = mB[r].y >> fr,
               sz = mB[r].z >> fr, sw = mB[r].w >> fr;
      unsigned bits[8] = { sx & 1u, (sx >> 16) & 1u, sy & 1u, (sy >> 16) & 1u,
                           sz & 1u, (sz >> 16) & 1u, sw & 1u, (sw >> 16) & 1u };
      float e[8];
      float ls = 0.f;
#pragma unroll
      for (int ni = 0; ni < 8; ni++) {
        float t = exp2f(praw[ni] - mr);
        t = bits[ni] ? t : 0.f;
        e[ni] = t; ls += t;
      }
      ls += __shfl_xor(ls, 1);
      ls += __shfl_xor(ls, 2);
      ls += __shfl_xor(ls, 4);
      ls += __shfl_xor(ls, 8);
      l_r[r] += ls;
#pragma unroll
      for (int a = 0; a < 4; a++) {
        unsigned pk = cvt_pk_bf16(e[2 * a], e[2 * a + 1]);
        Ps[w][g * 4 + r][a * 32 + fr]      = (ushort)pk;
        Ps[w][g * 4 + r][a * 32 + 16 + fr] = (ushort)(pk >> 16);
      }
    }

    // PV: O[16q][64d] += P[16q][128k] V[128k][64d]
#pragma unroll
    for (int ks = 0; ks < 4; ks++) {
      bf16x8 pf = *(const bf16x8*)&Ps[w][fr][ks * 32 + kg8];
#pragma unroll
      for (int ni = 0; ni < 4; ni++) {
        bf16x8 vf = *(const bf16x8*)&Vt[ni * 16 + fr][ks * 32 + kg8];
        accO[ni] = __builtin_amdgcn_mfma_f32_16x16x32_bf16(pf, vf, accO[ni], 0, 0, 0);
      }
    }
  }

  float inv[4];
#pragma unroll
  for (int r = 0; r < 4; r++) inv[r] = 1.f / l_r[r];
#pragma unroll
  for (int ni = 0; ni < 4; ni++) {
#pragma unroll
    for (int r = 0; r < 4; r++) {
      int qq = qrow4 + r;
      float o = accO[ni][r] * inv[r];
      X[((size_t)b * S + qq) * 768 + h * 64 + ni * 16 + fr] = f2bf(o);
    }
  }
}

extern "C" void kernel_launch(void* const* d_in, const int* in_sizes, int n_in,
                              void* d_out, int out_size, void* d_ws, size_t ws_size,
                              hipStream_t stream) {
  const float* q  = (const float*)d_in[0];
  const float* k  = (const float*)d_in[1];
  const float* v  = (const float*)d_in[2];
  const int* mask = (const int*)d_in[3];
  const float* wq = (const float*)d_in[4];
  const float* bq = (const float*)d_in[5];
  const float* wk = (const float*)d_in[6];
  const float* bk = (const float*)d_in[7];
  const float* wv = (const float*)d_in[8];
  const float* bv = (const float*)d_in[9];
  const float* wo = (const float*)d_in[10];
  const float* bo = (const float*)d_in[11];
  float* out = (float*)d_out;

  // ws: CV [3*NQ + 4*NW] | Qp | Kp | Vp | Xb  (ushort elems)
  ushort* CV = (ushort*)d_ws;
  ushort* Qp = CV + (size_t)3 * NQ + (size_t)4 * NW;
  ushort* Kp = Qp + NQ;
  ushort* Vp = Kp + NQ;
  ushort* Xb = Vp + NQ;
  // bitmask aliases the CV q-input region (dead after qkv_gemm2)
  unsigned long long* mbuf = (unsigned long long*)CV;

  cvt_all<<<11520, 256, 0, stream>>>(q, k, v, wq, wk, wv, wo, CV);
  qkv_gemm2<<<dim3(32, 18), dim3(256), 0, stream>>>(CV, bq, bk, bv, Qp, Kp, Vp);
  mask_pack<<<16384, 256, 0, stream>>>(mask, mbuf);
  attn_kernel<<<768, 256, 0, stream>>>(Qp, Kp, Vp, mbuf, Xb);
  o_gemm2<<<dim3(32, 6), dim3(256), 0, stream>>>(Xb, CV + (size_t)3 * NQ + (size_t)3 * NW, bo, out);
}